// Round 1
// baseline (2046.920 us; speedup 1.0000x reference)
//
#include <hip/hip_runtime.h>
#include <stdint.h>

#define BATCH 32768
#define DIM   256
#define NFEAT 4096
#define KTOP  32

// ---- order-preserving float<->uint mapping (ascending) ----
__device__ __forceinline__ uint32_t f2u(float f) {
    uint32_t b = __float_as_uint(f);
    return (b & 0x80000000u) ? ~b : (b | 0x80000000u);
}
__device__ __forceinline__ float u2f(uint32_t u) {
    uint32_t b = (u & 0x80000000u) ? (u ^ 0x80000000u) : ~u;
    return __uint_as_float(b);
}

// ---- kernel 1: xc = (x - mean)/std - b_dec ----
__global__ __launch_bounds__(256) void prep_xc(const float* __restrict__ x,
                                               const float* __restrict__ mean,
                                               const float* __restrict__ stdv,
                                               const float* __restrict__ b_dec,
                                               float* __restrict__ xc) {
    int g = blockIdx.x * 256 + threadIdx.x;       // float4 index
    int d0 = (g * 4) & (DIM - 1);                 // DIM divides 4-groups evenly
    float4 xv = ((const float4*)x)[g];
    float4 mv = *(const float4*)&mean[d0];
    float4 sv = *(const float4*)&stdv[d0];
    float4 bv = *(const float4*)&b_dec[d0];
    float4 o;
    o.x = (xv.x - mv.x) / sv.x - bv.x;
    o.y = (xv.y - mv.y) / sv.y - bv.y;
    o.z = (xv.z - mv.z) / sv.z - bv.z;
    o.w = (xv.w - mv.w) / sv.w - bv.w;
    ((float4*)xc)[g] = o;
}

// ---- kernel 2: W_decT[n][d] = W_dec[d][n] ----
__global__ __launch_bounds__(256) void transpose_wdec(const float* __restrict__ wd,
                                                      float* __restrict__ wdt) {
    __shared__ float t[32][33];
    int bx = blockIdx.x;              // n tile
    int by = blockIdx.y;              // d tile
    int lx = threadIdx.x & 31, ly = threadIdx.x >> 5;   // ly: 0..7
#pragma unroll
    for (int i = 0; i < 4; i++) {
        int d = by * 32 + ly + i * 8;
        t[ly + i * 8][lx] = wd[(size_t)d * NFEAT + bx * 32 + lx];
    }
    __syncthreads();
#pragma unroll
    for (int i = 0; i < 4; i++) {
        int n = bx * 32 + ly + i * 8;
        wdt[(size_t)n * DIM + by * 32 + lx] = t[lx][ly + i * 8];
    }
}

// ---- kernel 3: h_pre[b][n] = xc[b][:] . W_enc[n][:] + b_enc[n] ----
// f32 VALU GEMM (no fp32 MFMA on CDNA4). 128x128 tile, BK=8, 8x8 per thread.
__global__ __launch_bounds__(256) void encode_gemm(const float* __restrict__ A,   // xc [B][D]
                                                   const float* __restrict__ W,   // W_enc [N][D]
                                                   const float* __restrict__ be,  // b_enc [N]
                                                   float* __restrict__ hpre) {
    __shared__ float As[8][128];
    __shared__ float Bs[8][128];
    int bx = blockIdx.x;              // over N (fastest -> A-panel reuse is temporally local)
    int by = blockIdx.y;              // over B
    int tid = threadIdx.x;
    int row0 = by * 128, col0 = bx * 128;

    int ar = tid >> 1;                // 0..127 row within tile
    int ac = (tid & 1) * 4;           // 0 or 4
    const float* Ap = A + (size_t)(row0 + ar) * DIM + ac;
    const float* Wp = W + (size_t)(col0 + ar) * DIM + ac;

    int tx = tid & 15, ty = tid >> 4; // 16x16 thread grid

    float acc[8][8];
#pragma unroll
    for (int i = 0; i < 8; i++)
#pragma unroll
        for (int j = 0; j < 8; j++) acc[i][j] = 0.0f;

    for (int ko = 0; ko < DIM; ko += 8) {
        float4 av = *(const float4*)(Ap + ko);
        float4 wv = *(const float4*)(Wp + ko);
        __syncthreads();
        As[ac + 0][ar] = av.x; As[ac + 1][ar] = av.y;
        As[ac + 2][ar] = av.z; As[ac + 3][ar] = av.w;
        Bs[ac + 0][ar] = wv.x; Bs[ac + 1][ar] = wv.y;
        Bs[ac + 2][ar] = wv.z; Bs[ac + 3][ar] = wv.w;
        __syncthreads();
#pragma unroll
        for (int kk = 0; kk < 8; kk++) {
            float a[8], b[8];
            *(float4*)(a)     = *(const float4*)&As[kk][ty * 8];
            *(float4*)(a + 4) = *(const float4*)&As[kk][ty * 8 + 4];
            *(float4*)(b)     = *(const float4*)&Bs[kk][tx * 8];
            *(float4*)(b + 4) = *(const float4*)&Bs[kk][tx * 8 + 4];
#pragma unroll
            for (int i = 0; i < 8; i++)
#pragma unroll
                for (int j = 0; j < 8; j++) acc[i][j] += a[i] * b[j];
        }
    }

    float bev[8];
#pragma unroll
    for (int j = 0; j < 8; j++) bev[j] = be[col0 + tx * 8 + j];
#pragma unroll
    for (int i = 0; i < 8; i++) {
        int r = row0 + ty * 8 + i;
        float4 o0, o1;
        o0.x = acc[i][0] + bev[0]; o0.y = acc[i][1] + bev[1];
        o0.z = acc[i][2] + bev[2]; o0.w = acc[i][3] + bev[3];
        o1.x = acc[i][4] + bev[4]; o1.y = acc[i][5] + bev[5];
        o1.z = acc[i][6] + bev[6]; o1.w = acc[i][7] + bev[7];
        float* op = hpre + (size_t)r * NFEAT + col0 + tx * 8;
        *(float4*)op = o0;
        *(float4*)(op + 4) = o1;
    }
}

// ---- kernel 4: per-row top-K (radix select) + h_sparse write + sparse decode ----
__global__ __launch_bounds__(256) void topk_decode(const float* __restrict__ hpre,
                                                   const float* __restrict__ wdt,   // [N][D]
                                                   const float* __restrict__ b_dec,
                                                   float* __restrict__ hsp,
                                                   float* __restrict__ xhat) {
    int row = blockIdx.x;
    int tid = threadIdx.x;
    __shared__ uint32_t hist[256];
    __shared__ uint32_t sfx[257];
    __shared__ float cval[KTOP];
    __shared__ int   cidx[KTOP];
    __shared__ int   eqidx[64];
    __shared__ int   ccnt, eqcnt, selBin;

    uint32_t uu[16];
    const float* rp = hpre + (size_t)row * NFEAT;
#pragma unroll
    for (int i = 0; i < 16; i++) uu[i] = f2u(rp[i * 256 + tid]);

    uint32_t pref = 0;
    int kRem = KTOP;
    for (int p = 0; p < 4; p++) {
        int shift = 24 - 8 * p;
        hist[tid] = 0;
        __syncthreads();
#pragma unroll
        for (int i = 0; i < 16; i++) {
            uint32_t u = uu[i];
            bool ok = (p == 0) || ((u >> (shift + 8)) == pref);
            if (ok) atomicAdd(&hist[(u >> shift) & 255u], 1u);
        }
        __syncthreads();
        sfx[tid] = hist[tid];
        if (tid == 0) sfx[256] = 0;
        __syncthreads();
        for (int off = 1; off < 256; off <<= 1) {
            uint32_t v = (tid + off < 256) ? sfx[tid + off] : 0u;
            __syncthreads();
            sfx[tid] += v;
            __syncthreads();
        }
        // unique bin with sfx[t] >= kRem > sfx[t+1]
        if (sfx[tid] >= (uint32_t)kRem && sfx[tid + 1] < (uint32_t)kRem) selBin = tid;
        __syncthreads();
        int sb = selBin;
        kRem -= (int)sfx[sb + 1];
        pref = (pref << 8) | (uint32_t)sb;
        __syncthreads();
    }
    // pref == exact K-th largest key; kRem == #ties to keep (index order, jax semantics)

    if (tid == 0) { ccnt = 0; eqcnt = 0; }
    __syncthreads();

    float* hrow = hsp + (size_t)row * NFEAT;
#pragma unroll
    for (int i = 0; i < 16; i++) {
        int n = i * 256 + tid;
        uint32_t u = uu[i];
        float w = 0.0f;
        if (u > pref) {
            int s = atomicAdd(&ccnt, 1);
            float f = u2f(u);
            cval[s] = f; cidx[s] = n;
            w = f;
        } else if (u == pref) {
            int e = atomicAdd(&eqcnt, 1);
            if (e < 64) eqidx[e] = n;
        }
        hrow[n] = w;
    }
    __syncthreads();

    if (tid == 0) {
        int e = eqcnt; if (e > 64) e = 64;
        for (int a = 1; a < e; a++) {          // tiny insertion sort by index
            int v = eqidx[a]; int b2 = a - 1;
            while (b2 >= 0 && eqidx[b2] > v) { eqidx[b2 + 1] = eqidx[b2]; b2--; }
            eqidx[b2 + 1] = v;
        }
        int base = ccnt;                        // == KTOP - kRem
        float thrf = u2f(pref);
        for (int j = 0; j < kRem && j < e && (base + j) < KTOP; j++) {
            int n = eqidx[j];
            cidx[base + j] = n; cval[base + j] = thrf;
            hrow[n] = thrf;
        }
    }
    __syncthreads();

    // sparse decode: x_hat[row][d] = b_dec[d] + sum_k cval[k] * W_decT[cidx[k]][d]
    float accv = b_dec[tid];
#pragma unroll 8
    for (int k2 = 0; k2 < KTOP; k2++) {
        accv += cval[k2] * wdt[(size_t)cidx[k2] * DIM + tid];
    }
    xhat[(size_t)row * DIM + tid] = accv;
}

extern "C" void kernel_launch(void* const* d_in, const int* in_sizes, int n_in,
                              void* d_out, int out_size, void* d_ws, size_t ws_size,
                              hipStream_t stream) {
    const float* x     = (const float*)d_in[0];
    const float* W_enc = (const float*)d_in[1];
    const float* b_enc = (const float*)d_in[2];
    const float* W_dec = (const float*)d_in[3];
    const float* b_dec = (const float*)d_in[4];
    const float* mean  = (const float*)d_in[5];
    const float* stdv  = (const float*)d_in[6];

    float* out  = (float*)d_out;
    float* xhat = out;                                   // (B, D)
    float* hsp  = out + (size_t)BATCH * DIM;             // (B, N)
    float* hpre = hsp + (size_t)BATCH * NFEAT;           // (B, N)

    float* xc  = (float*)d_ws;                           // B*D f32   (33.5 MB)
    float* wdt = xc + (size_t)BATCH * DIM;               // N*D f32   (4.2 MB)

    prep_xc<<<(BATCH * DIM) / 1024, 256, 0, stream>>>(x, mean, stdv, b_dec, xc);
    transpose_wdec<<<dim3(NFEAT / 32, DIM / 32), 256, 0, stream>>>(W_dec, wdt);
    encode_gemm<<<dim3(NFEAT / 128, BATCH / 128), 256, 0, stream>>>(xc, W_enc, b_enc, hpre);
    topk_decode<<<BATCH, 256, 0, stream>>>(hpre, wdt, b_dec, hsp, xhat);
}